// Round 4
// baseline (901.469 us; speedup 1.0000x reference)
//
#include <hip/hip_runtime.h>
#include <hip/hip_bf16.h>

// Problem constants (B=32, D=256, H=W=64, K=6, CTX=256, TEMP=0.5)
#define NB 32
#define ND 256
#define NN_ 4096
#define NK 6

typedef short bf16x8 __attribute__((ext_vector_type(8)));
typedef float f32x4 __attribute__((ext_vector_type(4)));

__device__ __forceinline__ float bf2f(unsigned int u) {
    union { unsigned int i; float f; } v; v.i = (u & 0xffffu) << 16; return v.f;
}
__device__ __forceinline__ unsigned short f2bf(float f) {
    __hip_bfloat16 h = __float2bfloat16(f);
    return *reinterpret_cast<unsigned short*>(&h);
}
__device__ __forceinline__ float gelu_exact(float x) {
    return 0.5f * x * (1.0f + erff(x * 0.70710678118654752f));
}

// ---------------- setup: weights->bf16, init mask/accs/sumev0, context MLP ----------------
// blocks [0,1059): elementwise prep; blocks [1059,1091): per-batch context MLP.
__global__ void k_setup(const float* __restrict__ kw, const float* __restrict__ vw,
                        unsigned short* __restrict__ kwb, unsigned short* __restrict__ vwb,
                        float* __restrict__ mask, float* __restrict__ accs,
                        float* __restrict__ sumev0,
                        const float* __restrict__ tc, const float* __restrict__ w1,
                        const float* __restrict__ b1, const float* __restrict__ w2,
                        const float* __restrict__ b2, float* __restrict__ clue) {
    __shared__ __align__(16) float tcs[256];
    __shared__ __align__(16) float h1[256];
    int blk = blockIdx.x, t = threadIdx.x;
    if (blk < 1059) {
        int i = blk * 256 + t;
        if (i < 65536) kwb[i] = f2bf(kw[i]);
        else if (i < 131072) vwb[i - 65536] = f2bf(vw[i - 65536]);
        else if (i < 262144) mask[i - 131072] = 1.f;
        else if (i < 262912) accs[i - 262144] = 0.f;     // [6][4][32]
        else if (i < 271104) sumev0[i - 262912] = 0.f;   // [32][256]
        return;
    }
    int b = blk - 1059;
    tcs[t] = tc[b * 256 + t];
    __syncthreads();
    const float4* wr = (const float4*)(w1 + (size_t)t * 256);
    const float4* xs = (const float4*)tcs;
    float acc = b1[t];
#pragma unroll 8
    for (int i = 0; i < 64; ++i) {
        float4 w = wr[i], x = xs[i];
        acc += w.x * x.x + w.y * x.y + w.z * x.z + w.w * x.w;
    }
    h1[t] = gelu_exact(acc);
    __syncthreads();
    const float4* hs = (const float4*)h1;
    for (int r = 0; r < 6; ++r) {
        int row = r * 256 + t;
        const float4* w2r = (const float4*)(w2 + (size_t)row * 256);
        float a2 = b2[row];
#pragma unroll 8
        for (int i = 0; i < 64; ++i) {
            float4 w = w2r[i], x = hs[i];
            a2 += w.x * x.x + w.y * x.y + w.z * x.z + w.w * x.w;
        }
        clue[b * 1536 + row] = fminf(fmaxf(a2, -10.f), 10.f);
    }
}

// ---------------- fused transpose + LN + K/V projection (bf16 MFMA) ----------------
// block: 64 n-rows of one batch. nt-outer: B-frags for one 16-n tile held in regs
// (32 VGPRs), each LDS element read ONCE per wave (32 ds_read_b128/wave total).
__global__ __launch_bounds__(256, 4) void k_kv(
    const float* __restrict__ features, const float* __restrict__ fn_g,
    const float* __restrict__ fn_b, const unsigned short* __restrict__ kwb,
    const unsigned short* __restrict__ vwb, const float* __restrict__ kb,
    const float* __restrict__ vb, unsigned short* __restrict__ kp,
    unsigned short* __restrict__ vp) {
    int tile = blockIdx.x, b = blockIdx.y;
    int n0 = tile * 64;
    int t = threadIdx.x;

    __shared__ __align__(16) unsigned short A[64][264];   // bf16 feats tile [n][d]

    // phase 1: thread t: dd = t&15 (d-pair set), nq = t>>4 (n-quad). float4 loads.
    int dd = t & 15, nq = t >> 4;
    const float* fb = features + (size_t)b * 1048576 + n0 + nq * 4;
    unsigned int pk[8][4];   // [p][k]: packed bf16 (d0 | d0+1<<16) for n = nq*4+k
    float s[4] = {0, 0, 0, 0}, s2[4] = {0, 0, 0, 0};
#pragma unroll
    for (int p = 0; p < 8; ++p) {
        int d0 = p * 32 + dd * 2;
        float4 a0 = *reinterpret_cast<const float4*>(fb + (size_t)d0 * 4096);
        float4 a1 = *reinterpret_cast<const float4*>(fb + (size_t)(d0 + 1) * 4096);
        s[0] += a0.x + a1.x; s2[0] += a0.x * a0.x + a1.x * a1.x;
        s[1] += a0.y + a1.y; s2[1] += a0.y * a0.y + a1.y * a1.y;
        s[2] += a0.z + a1.z; s2[2] += a0.z * a0.z + a1.z * a1.z;
        s[3] += a0.w + a1.w; s2[3] += a0.w * a0.w + a1.w * a1.w;
        pk[p][0] = (unsigned int)f2bf(a0.x) | ((unsigned int)f2bf(a1.x) << 16);
        pk[p][1] = (unsigned int)f2bf(a0.y) | ((unsigned int)f2bf(a1.y) << 16);
        pk[p][2] = (unsigned int)f2bf(a0.z) | ((unsigned int)f2bf(a1.z) << 16);
        pk[p][3] = (unsigned int)f2bf(a0.w) | ((unsigned int)f2bf(a1.w) << 16);
    }
#pragma unroll
    for (int m = 1; m < 16; m <<= 1) {
#pragma unroll
        for (int k = 0; k < 4; ++k) {
            s[k] += __shfl_xor(s[k], m, 64);
            s2[k] += __shfl_xor(s2[k], m, 64);
        }
    }
    float mm[4], rr[4];
#pragma unroll
    for (int k = 0; k < 4; ++k) {
        float mean = s[k] * (1.f / 256.f);
        float var = s2[k] * (1.f / 256.f) - mean * mean;
        mm[k] = mean; rr[k] = rsqrtf(var + 1e-5f);
    }
#pragma unroll
    for (int p = 0; p < 8; ++p) {
        int d0 = p * 32 + dd * 2;
        float g0 = fn_g[d0], g1 = fn_g[d0 + 1];
        float e0 = fn_b[d0], e1 = fn_b[d0 + 1];
#pragma unroll
        for (int k = 0; k < 4; ++k) {
            float x0 = bf2f(pk[p][k]);
            float x1 = bf2f(pk[p][k] >> 16);
            unsigned int lo = f2bf((x0 - mm[k]) * rr[k] * g0 + e0);
            unsigned int hi = f2bf((x1 - mm[k]) * rr[k] * g1 + e1);
            *reinterpret_cast<unsigned int*>(&A[nq * 4 + k][d0]) = lo | (hi << 16);
        }
    }
    __syncthreads();

    // phase 2/3: wave wv owns douts [wv*64, wv*64+64). nt outer, bfrag in regs.
    int lane = t & 63, wv = t >> 6;
    int r = lane & 15, qd = lane >> 4;
#pragma unroll
    for (int nt = 0; nt < 4; ++nt) {
        bf16x8 bfrag[8];
#pragma unroll
        for (int ks = 0; ks < 8; ++ks)
            bfrag[ks] = *reinterpret_cast<const bf16x8*>(&A[nt * 16 + r][ks * 32 + qd * 8]);
#pragma unroll
        for (int mat = 0; mat < 2; ++mat) {
            const unsigned short* wb = mat ? vwb : kwb;
            const float* bias = mat ? vb : kb;
            unsigned short* outp = mat ? vp : kp;
#pragma unroll
            for (int dtl = 0; dtl < 4; ++dtl) {
                int dt = wv * 4 + dtl;
                const unsigned short* wrow = wb + (size_t)(dt * 16 + r) * 256 + qd * 8;
                f32x4 acc = {0.f, 0.f, 0.f, 0.f};
#pragma unroll
                for (int ks = 0; ks < 8; ++ks) {
                    bf16x8 af = *reinterpret_cast<const bf16x8*>(wrow + ks * 32);
                    acc = __builtin_amdgcn_mfma_f32_16x16x32_bf16(af, bfrag[ks], acc, 0, 0, 0);
                }
                int dbase = dt * 16 + qd * 4;
                unsigned int lo = ((unsigned int)f2bf(acc[1] + bias[dbase + 1]) << 16)
                                | (unsigned int)f2bf(acc[0] + bias[dbase]);
                unsigned int hi = ((unsigned int)f2bf(acc[3] + bias[dbase + 3]) << 16)
                                | (unsigned int)f2bf(acc[2] + bias[dbase + 2]);
                int n_g = n0 + nt * 16 + r;
                *reinterpret_cast<uint2*>(outp + ((size_t)(b * 4096 + n_g)) * 256 + dbase)
                    = make_uint2(lo, hi);
            }
        }
    }
}

// ---------------- B: GRU-combine + LN + q + scores + Σe·v (kp AND vp in one pass) ----------------
__global__ __launch_bounds__(256, 4) void k_qscore(
    const float* __restrict__ clue, const float* __restrict__ gacc,
    const float* __restrict__ state_prev, float* __restrict__ state_cur,
    const float* __restrict__ qn_g, const float* __restrict__ qn_b,
    const float* __restrict__ q_w, const float* __restrict__ q_b,
    const unsigned short* __restrict__ kp, const unsigned short* __restrict__ vp,
    const float* __restrict__ mask, float* __restrict__ escore,
    float* __restrict__ accs, float* __restrict__ sumev,
    float* __restrict__ sumev_other, int kstep) {
    int c = blockIdx.x, b = blockIdx.y, t = threadIdx.x;
    int lane = t & 63, wv = t >> 6;
    __shared__ __align__(16) float qs[256];
    __shared__ float ash[256];
    __shared__ __align__(16) float part[8][264];
    __shared__ float sred[8];
    // combine previous step's GRU gates -> h (state for this step)
    float h = 0.f;
    if (kstep > 0) {
        float sr = gacc[(b * 4 + 0) * 256 + t];
        float sz = gacc[(b * 4 + 1) * 256 + t];
        float gin = gacc[(b * 4 + 2) * 256 + t];
        float ghn = gacc[(b * 4 + 3) * 256 + t];
        float r = 1.f / (1.f + expf(-sr));
        float z = 1.f / (1.f + expf(-sz));
        float nv = tanhf(gin + r * ghn);
        h = (1.f - z) * nv + z * state_prev[b * 256 + t];
    }
    if (c == 0) {
        state_cur[b * 256 + t] = h;
        sumev_other[b * 256 + t] = 0.f;   // zero the k+1 buffer (untouched this step)
    }
    // LN(clue + h)
    float x = clue[(b * 6 + kstep) * 256 + t] + h;
    float s = x, s2 = x * x;
#pragma unroll
    for (int off = 32; off > 0; off >>= 1) {
        s += __shfl_down(s, off, 64);
        s2 += __shfl_down(s2, off, 64);
    }
    if (lane == 0) { sred[wv] = s; sred[4 + wv] = s2; }
    __syncthreads();
    float muv = (sred[0] + sred[1] + sred[2] + sred[3]) * (1.f / 256.f);
    float var = (sred[4] + sred[5] + sred[6] + sred[7]) * (1.f / 256.f) - muv * muv;
    float rs = rsqrtf(var + 1e-5f);
    qs[t] = (x - muv) * rs * qn_g[t] + qn_b[t];
    __syncthreads();
    // q projection (each block computes the full q vector redundantly)
    const float4* wr = (const float4*)(q_w + (size_t)t * 256);
    const float4* xs4 = (const float4*)qs;
    float qv = q_b[t];
#pragma unroll 8
    for (int i = 0; i < 64; ++i) {
        float4 w = wr[i], xx = xs4[i];
        qv += w.x * xx.x + w.y * xx.y + w.z * xx.z + w.w * xx.w;
    }
    __syncthreads();
    qs[t] = qv;
    __syncthreads();
    // scores: 8 lanes per kp row (128B contiguous chunks), shfl_xor dot reduce
    int l = t & 7, rg = t >> 3;
    float dsum = 0.f;
#pragma unroll
    for (int pp = 0; pp < 8; ++pp) {
        int nl = pp * 32 + rg;
        int n = c * 256 + nl;
        const uint4* kr = reinterpret_cast<const uint4*>(kp + ((size_t)(b * 4096 + n)) * 256 + l * 8);
        float dot = 0.f;
#pragma unroll
        for (int j = 0; j < 4; ++j) {
            uint4 rv = kr[j * 8];                       // stride 64 elems = 128 B
            const float* qq = qs + j * 64 + l * 8;
            dot += bf2f(rv.x) * qq[0] + bf2f(rv.x >> 16) * qq[1]
                 + bf2f(rv.y) * qq[2] + bf2f(rv.y >> 16) * qq[3]
                 + bf2f(rv.z) * qq[4] + bf2f(rv.z >> 16) * qq[5]
                 + bf2f(rv.w) * qq[6] + bf2f(rv.w >> 16) * qq[7];
        }
        dot += __shfl_xor(dot, 1, 64);
        dot += __shfl_xor(dot, 2, 64);
        dot += __shfl_xor(dot, 4, 64);
        float sc = dot * 0.0625f + logf(mask[(size_t)b * 4096 + n]);
        sc = fminf(fmaxf(sc, -50.f), 50.f);
        float lg = fminf(fmaxf(sc * 2.f, -50.f), 50.f);   // /TEMP, TEMP=0.5
        float e = expf(lg);
        if (l == 0) {
            escore[(size_t)b * 4096 + n] = e;
            ash[nl] = e;
        }
        dsum += e;
    }
    dsum *= 0.125f;   // each e counted by 8 lanes
#pragma unroll
    for (int off = 32; off > 0; off >>= 1) dsum += __shfl_down(dsum, off, 64);
    if (lane == 0) sred[wv] = dsum;
    __syncthreads();
    if (t == 0) atomicAdd(&accs[kstep * 128 + b], sred[0] + sred[1] + sred[2] + sred[3]);
    // Σ e·v partials: thread owns 8 douts, sweeps 32 n rows (uint4 = 16B/lane)
    int dbase = (t & 31) * 8, noff = t >> 5;
    const unsigned short* vb = vp + ((size_t)(b * 4096 + c * 256 + noff * 32)) * 256 + dbase;
    float a0 = 0, a1 = 0, a2 = 0, a3 = 0, a4 = 0, a5 = 0, a6 = 0, a7 = 0;
#pragma unroll 4
    for (int j = 0; j < 32; ++j) {
        uint4 rv = *reinterpret_cast<const uint4*>(vb + (size_t)j * 256);
        float w = ash[noff * 32 + j];
        a0 += w * bf2f(rv.x); a1 += w * bf2f(rv.x >> 16);
        a2 += w * bf2f(rv.y); a3 += w * bf2f(rv.y >> 16);
        a4 += w * bf2f(rv.z); a5 += w * bf2f(rv.z >> 16);
        a6 += w * bf2f(rv.w); a7 += w * bf2f(rv.w >> 16);
    }
    *reinterpret_cast<float4*>(&part[noff][dbase])     = make_float4(a0, a1, a2, a3);
    *reinterpret_cast<float4*>(&part[noff][dbase + 4]) = make_float4(a4, a5, a6, a7);
    __syncthreads();
    float sum = part[0][t] + part[1][t] + part[2][t] + part[3][t]
              + part[4][t] + part[5][t] + part[6][t] + part[7][t];
    atomicAdd(&sumev[b * 256 + t], sum);
}

// ---------------- C (light): normalize escore -> amap, centroid/entropy, mask ----------------
__global__ __launch_bounds__(256, 4) void k_attn2(
    const float* __restrict__ escore, float* __restrict__ mask,
    float* __restrict__ accs, float* __restrict__ out_amap, int kstep) {
    int c = blockIdx.x, b = blockIdx.y, t = threadIdx.x;
    int lane = t & 63, wv = t >> 6;
    __shared__ float sred[12];
    int n4 = (c * 256 + t) * 4;   // 4 n per thread, float4
    float inv = 1.f / accs[kstep * 128 + b];
    float4 e4 = *reinterpret_cast<const float4*>(&escore[(size_t)b * 4096 + n4]);
    float4 m4 = *reinterpret_cast<const float4*>(&mask[(size_t)b * 4096 + n4]);
    float a[4] = {fmaxf(e4.x * inv, 1e-8f), fmaxf(e4.y * inv, 1e-8f),
                  fmaxf(e4.z * inv, 1e-8f), fmaxf(e4.w * inv, 1e-8f)};
    *reinterpret_cast<float4*>(&out_amap[((size_t)(b * 6 + kstep)) * 4096 + n4])
        = make_float4(a[0], a[1], a[2], a[3]);
    float mv[4] = {m4.x, m4.y, m4.z, m4.w};
    float s0 = 0.f, s1 = 0.f, s2 = 0.f;
#pragma unroll
    for (int j = 0; j < 4; ++j) {
        int n = n4 + j;
        s0 += a[j] * (float)(n >> 6);
        s1 += a[j] * (float)(n & 63);
        float ac = fmaxf(a[j], 1e-6f);
        s2 += ac * logf(ac);
        mv[j] = fmaxf(mv[j] * (1.f - 0.9f * a[j]), 1e-6f);
    }
    *reinterpret_cast<float4*>(&mask[(size_t)b * 4096 + n4])
        = make_float4(mv[0], mv[1], mv[2], mv[3]);
#pragma unroll
    for (int off = 32; off > 0; off >>= 1) {
        s0 += __shfl_down(s0, off, 64);
        s1 += __shfl_down(s1, off, 64);
        s2 += __shfl_down(s2, off, 64);
    }
    if (lane == 0) { sred[wv] = s0; sred[4 + wv] = s1; sred[8 + wv] = s2; }
    __syncthreads();
    if (t == 0) {
        atomicAdd(&accs[kstep * 128 + 32 + b], sred[0] + sred[1] + sred[2] + sred[3]);
        atomicAdd(&accs[kstep * 128 + 64 + b], sred[4] + sred[5] + sred[6] + sred[7]);
        atomicAdd(&accs[kstep * 128 + 96 + b], sred[8] + sred[9] + sred[10] + sred[11]);
    }
}

// ---------------- D: GRU gate GEMVs (96 blocks) + stop head/centroid out (32 blocks) ----------------
__global__ __launch_bounds__(256, 2) void k_gate(
    const float* __restrict__ sumev, const float* __restrict__ state_cur,
    const float* __restrict__ wih, const float* __restrict__ bih,
    const float* __restrict__ whh, const float* __restrict__ bhh,
    const float* __restrict__ sw1, const float* __restrict__ sb1,
    const float* __restrict__ sw2, const float* __restrict__ sb2,
    const float* __restrict__ accs, float* __restrict__ gacc,
    float* __restrict__ out_cent, float* __restrict__ out_stop, int kstep) {
    int bb = blockIdx.x, t = threadIdx.x;
    int lane = t & 63, wv = t >> 6;
    __shared__ __align__(16) float att[256];
    __shared__ __align__(16) float st[256];
    __shared__ float sred[4];
    if (bb < 96) {
        if (kstep == 5) return;   // gates feed h(k+1); unused after last step
        int b = bb & 31, g = bb >> 5;
        float inv = 1.f / accs[kstep * 128 + b];
        att[t] = sumev[b * 256 + t] * inv;
        st[t] = state_cur[b * 256 + t];
        __syncthreads();
        int row = g * 256 + t;
        const float4* wi = (const float4*)(wih + (size_t)row * 256);
        const float4* wh = (const float4*)(whh + (size_t)row * 256);
        const float4* av = (const float4*)att;
        const float4* sv = (const float4*)st;
        float ai = bih[row], ah = bhh[row];
#pragma unroll 4
        for (int i = 0; i < 64; ++i) {
            float4 w1 = wi[i], x1 = av[i];
            ai += w1.x * x1.x + w1.y * x1.y + w1.z * x1.z + w1.w * x1.w;
            float4 w2 = wh[i], x2 = sv[i];
            ah += w2.x * x2.x + w2.y * x2.y + w2.z * x2.z + w2.w * x2.w;
        }
        if (g == 2) {
            gacc[(b * 4 + 2) * 256 + t] = ai;
            gacc[(b * 4 + 3) * 256 + t] = ah;
        } else {
            gacc[(b * 4 + g) * 256 + t] = ai + ah;
        }
    } else {
        int b = bb - 96;
        float inv = 1.f / accs[kstep * 128 + b];
        att[t] = sumev[b * 256 + t] * inv;
        __syncthreads();
        float entv = -accs[kstep * 128 + 96 + b] * 0.12022458674074826f; // 1/log(4096+1e-6)
        float v = 0.f;
        if (t < 128) {
            const float* wr = sw1 + (size_t)t * 257;
            float acc = sb1[t];
#pragma unroll 8
            for (int i = 0; i < 256; ++i) acc += att[i] * wr[i];
            acc += entv * wr[256];
            v = gelu_exact(acc) * sw2[t];
        }
#pragma unroll
        for (int off = 32; off > 0; off >>= 1) v += __shfl_down(v, off, 64);
        if (lane == 0) sred[wv] = v;
        __syncthreads();
        if (t == 0) {
            float sraw = sb2[0] + sred[0] + sred[1] + sred[2] + sred[3];
            out_stop[b * 6 + kstep] = 4.f * tanhf(sraw * 0.25f);
            out_cent[(b * 6 + kstep) * 2 + 0] = accs[kstep * 128 + 32 + b];
            out_cent[(b * 6 + kstep) * 2 + 1] = accs[kstep * 128 + 64 + b];
        }
    }
}

extern "C" void kernel_launch(void* const* d_in, const int* in_sizes, int n_in,
                              void* d_out, int out_size, void* d_ws, size_t ws_size,
                              hipStream_t stream) {
    const float* features     = (const float*)d_in[0];
    const float* task_context = (const float*)d_in[1];
    const float* ctx_w1 = (const float*)d_in[2];
    const float* ctx_b1 = (const float*)d_in[3];
    const float* ctx_w2 = (const float*)d_in[4];
    const float* ctx_b2 = (const float*)d_in[5];
    const float* q_w = (const float*)d_in[6];
    const float* q_b = (const float*)d_in[7];
    const float* k_w = (const float*)d_in[8];
    const float* k_b = (const float*)d_in[9];
    const float* v_w = (const float*)d_in[10];
    const float* v_b = (const float*)d_in[11];
    const float* qn_g = (const float*)d_in[12];
    const float* qn_b = (const float*)d_in[13];
    const float* fn_g = (const float*)d_in[14];
    const float* fn_b = (const float*)d_in[15];
    const float* stop_w1 = (const float*)d_in[16];
    const float* stop_b1 = (const float*)d_in[17];
    const float* stop_w2 = (const float*)d_in[18];
    const float* stop_b2 = (const float*)d_in[19];
    const float* gru_wih = (const float*)d_in[20];
    const float* gru_bih = (const float*)d_in[21];
    const float* gru_whh = (const float*)d_in[22];
    const float* gru_bhh = (const float*)d_in[23];

    // workspace layout (~136 MB)
    unsigned short* kwb = (unsigned short*)d_ws;
    unsigned short* vwb = kwb + 65536;
    unsigned short* kp  = vwb + 65536;
    unsigned short* vp  = kp + (size_t)NB * NN_ * ND;
    float* clue     = (float*)(vp + (size_t)NB * NN_ * ND);
    float* state0   = clue + NB * NK * ND;
    float* state1   = state0 + NB * ND;
    float* sumev0   = state1 + NB * ND;
    float* sumev1   = sumev0 + NB * ND;
    float* mask     = sumev1 + NB * ND;
    float* escore   = mask + NB * NN_;
    float* accs     = escore + NB * NN_;      // [6][4][32]: denom,rowc,colc,ent
    float* gacc     = accs + NK * 4 * NB;     // [32][4][256]

    float* out_cent = (float*)d_out;          // (B,K,2)
    float* out_amap = out_cent + NB * NK * 2; // (B,K,H,W)
    float* out_stop = out_amap + (size_t)NB * NK * NN_; // (B,K)

    float* stbuf[2] = {state0, state1};
    float* evbuf[2] = {sumev0, sumev1};

    k_setup<<<1091, 256, 0, stream>>>(k_w, v_w, kwb, vwb, mask, accs, sumev0,
                                      task_context, ctx_w1, ctx_b1, ctx_w2, ctx_b2, clue);
    k_kv<<<dim3(64, 32), 256, 0, stream>>>(features, fn_g, fn_b, kwb, vwb, k_b, v_b, kp, vp);
    for (int k = 0; k < NK; ++k) {
        float* scur = stbuf[k & 1];
        float* sprev = stbuf[1 - (k & 1)];
        float* ev = evbuf[k & 1];
        float* evo = evbuf[1 - (k & 1)];
        k_qscore<<<dim3(16, 32), 256, 0, stream>>>(clue, gacc, sprev, scur, qn_g, qn_b,
                                                   q_w, q_b, kp, vp, mask, escore, accs,
                                                   ev, evo, k);
        k_attn2<<<dim3(4, 32), 256, 0, stream>>>(escore, mask, accs, out_amap, k);
        k_gate<<<128, 256, 0, stream>>>(ev, scur, gru_wih, gru_bih, gru_whh, gru_bhh,
                                        stop_w1, stop_b1, stop_w2, stop_b2, accs, gacc,
                                        out_cent, out_stop, k);
    }
}

// Round 5
// 732.148 us; speedup vs baseline: 1.2313x; 1.2313x over previous
//
#include <hip/hip_runtime.h>
#include <hip/hip_bf16.h>

// Problem constants (B=32, D=256, H=W=64, K=6, CTX=256, TEMP=0.5)
#define NB 32
#define ND 256
#define NN_ 4096
#define NK 6

typedef short bf16x8 __attribute__((ext_vector_type(8)));
typedef float f32x4 __attribute__((ext_vector_type(4)));

__device__ __forceinline__ float bf2f(unsigned int u) {
    union { unsigned int i; float f; } v; v.i = (u & 0xffffu) << 16; return v.f;
}
__device__ __forceinline__ unsigned short f2bf(float f) {
    __hip_bfloat16 h = __float2bfloat16(f);
    return *reinterpret_cast<unsigned short*>(&h);
}
__device__ __forceinline__ float gelu_exact(float x) {
    return 0.5f * x * (1.0f + erff(x * 0.70710678118654752f));
}

// ---------------- setup: weights->bf16, init mask/accs/sumev0, context MLP ----------------
__global__ void k_setup(const float* __restrict__ kw, const float* __restrict__ vw,
                        unsigned short* __restrict__ kwb, unsigned short* __restrict__ vwb,
                        float* __restrict__ mask, float* __restrict__ accs,
                        float* __restrict__ sumev0,
                        const float* __restrict__ tc, const float* __restrict__ w1,
                        const float* __restrict__ b1, const float* __restrict__ w2,
                        const float* __restrict__ b2, float* __restrict__ clue) {
    __shared__ __align__(16) float tcs[256];
    __shared__ __align__(16) float h1[256];
    int blk = blockIdx.x, t = threadIdx.x;
    if (blk < 1059) {
        int i = blk * 256 + t;
        if (i < 65536) kwb[i] = f2bf(kw[i]);
        else if (i < 131072) vwb[i - 65536] = f2bf(vw[i - 65536]);
        else if (i < 262144) mask[i - 131072] = 1.f;
        else if (i < 262912) accs[i - 262144] = 0.f;     // [6][4][32]
        else if (i < 271104) sumev0[i - 262912] = 0.f;   // [32][256]
        return;
    }
    int b = blk - 1059;
    tcs[t] = tc[b * 256 + t];
    __syncthreads();
    const float4* wr = (const float4*)(w1 + (size_t)t * 256);
    const float4* xs = (const float4*)tcs;
    float acc = b1[t];
#pragma unroll 8
    for (int i = 0; i < 64; ++i) {
        float4 w = wr[i], x = xs[i];
        acc += w.x * x.x + w.y * x.y + w.z * x.z + w.w * x.w;
    }
    h1[t] = gelu_exact(acc);
    __syncthreads();
    const float4* hs = (const float4*)h1;
    for (int r = 0; r < 6; ++r) {
        int row = r * 256 + t;
        const float4* w2r = (const float4*)(w2 + (size_t)row * 256);
        float a2 = b2[row];
#pragma unroll 8
        for (int i = 0; i < 64; ++i) {
            float4 w = w2r[i], x = hs[i];
            a2 += w.x * x.x + w.y * x.y + w.z * x.z + w.w * x.w;
        }
        clue[b * 1536 + row] = fminf(fmaxf(a2, -10.f), 10.f);
    }
}

// ---------------- fused transpose + LN + K/V projection (bf16 MFMA) ----------------
// block: 128 n-rows. A staged in MFMA-fragment order (64 KB LDS, conflict-free b128
// reads). bfrag held in regs for 4 n-tiles; weights read once per (ntt,mat,dtl) and
// reused across 4 parallel MFMA chains -> L2 weight traffic 0.5 GB total.
__global__ __launch_bounds__(256, 2) void k_kv(
    const float* __restrict__ features, const float* __restrict__ fn_g,
    const float* __restrict__ fn_b, const unsigned short* __restrict__ kwb,
    const unsigned short* __restrict__ vwb, const float* __restrict__ kb,
    const float* __restrict__ vb, unsigned short* __restrict__ kp,
    unsigned short* __restrict__ vp) {
    int tile = blockIdx.x, b = blockIdx.y;
    int n0 = tile * 128;
    int t = threadIdx.x;

    // fragment layout: element (n,d) -> seg = (n>>4)*8 + (d>>5), pos = ((d>>3)&3)*16 + (n&15),
    // short index = (seg*64 + pos)*8 + (d&7). A wave's ds_read_b128 for (nt,ks): lane l
    // reads 16B at (seg*64+l)*16 B -> consecutive, conflict-free.
    __shared__ __align__(16) unsigned short A[32768];   // 64 KB
    unsigned int* A32 = reinterpret_cast<unsigned int*>(A);

    int dd = t & 15, nq = t >> 4;
#pragma unroll
    for (int hh = 0; hh < 2; ++hh) {
        const float* fb = features + (size_t)b * 1048576 + n0 + hh * 64 + nq * 4;
        unsigned int pk[8][4];
        float s[4] = {0, 0, 0, 0}, s2[4] = {0, 0, 0, 0};
#pragma unroll
        for (int p = 0; p < 8; ++p) {
            int d0 = p * 32 + dd * 2;
            float4 a0 = *reinterpret_cast<const float4*>(fb + (size_t)d0 * 4096);
            float4 a1 = *reinterpret_cast<const float4*>(fb + (size_t)(d0 + 1) * 4096);
            s[0] += a0.x + a1.x; s2[0] += a0.x * a0.x + a1.x * a1.x;
            s[1] += a0.y + a1.y; s2[1] += a0.y * a0.y + a1.y * a1.y;
            s[2] += a0.z + a1.z; s2[2] += a0.z * a0.z + a1.z * a1.z;
            s[3] += a0.w + a1.w; s2[3] += a0.w * a0.w + a1.w * a1.w;
            pk[p][0] = (unsigned int)f2bf(a0.x) | ((unsigned int)f2bf(a1.x) << 16);
            pk[p][1] = (unsigned int)f2bf(a0.y) | ((unsigned int)f2bf(a1.y) << 16);
            pk[p][2] = (unsigned int)f2bf(a0.z) | ((unsigned int)f2bf(a1.z) << 16);
            pk[p][3] = (unsigned int)f2bf(a0.w) | ((unsigned int)f2bf(a1.w) << 16);
        }
#pragma unroll
        for (int m = 1; m < 16; m <<= 1) {
#pragma unroll
            for (int k = 0; k < 4; ++k) {
                s[k] += __shfl_xor(s[k], m, 64);
                s2[k] += __shfl_xor(s2[k], m, 64);
            }
        }
        float mm[4], rr[4];
#pragma unroll
        for (int k = 0; k < 4; ++k) {
            float mean = s[k] * (1.f / 256.f);
            float var = s2[k] * (1.f / 256.f) - mean * mean;
            mm[k] = mean; rr[k] = rsqrtf(var + 1e-5f);
        }
        int qdw = dd >> 2, jw = dd & 3;
#pragma unroll
        for (int p = 0; p < 8; ++p) {
            int d0 = p * 32 + dd * 2;
            float g0 = fn_g[d0], g1 = fn_g[d0 + 1];
            float e0 = fn_b[d0], e1 = fn_b[d0 + 1];
#pragma unroll
            for (int k = 0; k < 4; ++k) {
                int ln = hh * 64 + nq * 4 + k;
                int nt = ln >> 4, r = ln & 15;
                float x0 = bf2f(pk[p][k]);
                float x1 = bf2f(pk[p][k] >> 16);
                unsigned int lo = f2bf((x0 - mm[k]) * rr[k] * g0 + e0);
                unsigned int hi = f2bf((x1 - mm[k]) * rr[k] * g1 + e1);
                A32[((nt * 8 + p) * 64 + qdw * 16 + r) * 4 + jw] = lo | (hi << 16);
            }
        }
    }
    __syncthreads();

    int lane = t & 63, wv = t >> 6;
    int r = lane & 15, qd = lane >> 4;
#pragma unroll
    for (int ntt = 0; ntt < 2; ++ntt) {
        bf16x8 bfrag[4][8];
#pragma unroll
        for (int q4 = 0; q4 < 4; ++q4)
#pragma unroll
            for (int ks = 0; ks < 8; ++ks)
                bfrag[q4][ks] = *reinterpret_cast<const bf16x8*>(
                    &A[(((ntt * 4 + q4) * 8 + ks) * 64 + lane) * 8]);
#pragma unroll
        for (int mat = 0; mat < 2; ++mat) {
            const unsigned short* wb = mat ? vwb : kwb;
            const float* bias = mat ? vb : kb;
            unsigned short* outp = mat ? vp : kp;
#pragma unroll
            for (int dtl = 0; dtl < 4; ++dtl) {
                int dt = wv * 4 + dtl;
                const unsigned short* wrow = wb + (size_t)(dt * 16 + r) * 256 + qd * 8;
                f32x4 acc0 = {0, 0, 0, 0}, acc1 = {0, 0, 0, 0};
                f32x4 acc2 = {0, 0, 0, 0}, acc3 = {0, 0, 0, 0};
#pragma unroll
                for (int ks = 0; ks < 8; ++ks) {
                    bf16x8 af = *reinterpret_cast<const bf16x8*>(wrow + ks * 32);
                    acc0 = __builtin_amdgcn_mfma_f32_16x16x32_bf16(af, bfrag[0][ks], acc0, 0, 0, 0);
                    acc1 = __builtin_amdgcn_mfma_f32_16x16x32_bf16(af, bfrag[1][ks], acc1, 0, 0, 0);
                    acc2 = __builtin_amdgcn_mfma_f32_16x16x32_bf16(af, bfrag[2][ks], acc2, 0, 0, 0);
                    acc3 = __builtin_amdgcn_mfma_f32_16x16x32_bf16(af, bfrag[3][ks], acc3, 0, 0, 0);
                }
                int dbase = dt * 16 + qd * 4;
                float b0_ = bias[dbase], b1_ = bias[dbase + 1];
                float b2_ = bias[dbase + 2], b3_ = bias[dbase + 3];
                f32x4 aa[4] = {acc0, acc1, acc2, acc3};
#pragma unroll
                for (int q4 = 0; q4 < 4; ++q4) {
                    int n_g = n0 + (ntt * 4 + q4) * 16 + r;
                    unsigned int lo = ((unsigned int)f2bf(aa[q4][1] + b1_) << 16)
                                    | (unsigned int)f2bf(aa[q4][0] + b0_);
                    unsigned int hi = ((unsigned int)f2bf(aa[q4][3] + b3_) << 16)
                                    | (unsigned int)f2bf(aa[q4][2] + b2_);
                    *reinterpret_cast<uint2*>(outp + ((size_t)(b * 4096 + n_g)) * 256 + dbase)
                        = make_uint2(lo, hi);
                }
            }
        }
    }
}

// ---------------- B: GRU-combine + LN + q + scores + Σe·v; c==16 blocks emit
// previous step's stop-logit + centroid outputs ----------------
__global__ __launch_bounds__(256, 4) void k_qscore(
    const float* __restrict__ clue, const float* __restrict__ gacc,
    const float* __restrict__ state_prev, float* __restrict__ state_cur,
    const float* __restrict__ qn_g, const float* __restrict__ qn_b,
    const float* __restrict__ q_w, const float* __restrict__ q_b,
    const unsigned short* __restrict__ kp, const unsigned short* __restrict__ vp,
    const float* __restrict__ mask, float* __restrict__ escore,
    float* __restrict__ accs, float* __restrict__ sumev,
    const float* __restrict__ sumev_prev,
    const float* __restrict__ sw1, const float* __restrict__ sb1,
    const float* __restrict__ sw2, const float* __restrict__ sb2,
    float* __restrict__ out_cent, float* __restrict__ out_stop, int kstep) {
    int c = blockIdx.x, b = blockIdx.y, t = threadIdx.x;
    int lane = t & 63, wv = t >> 6;
    __shared__ __align__(16) float qs[256];
    __shared__ float ash[256];
    __shared__ __align__(16) float part[8][264];
    __shared__ float sred[8];
    if (c == 16) {   // stop head + centroid out for step kstep-1
        if (kstep == 0) return;
        int kp_ = kstep - 1;
        float inv = 1.f / accs[kp_ * 128 + b];
        qs[t] = sumev_prev[b * 256 + t] * inv;
        __syncthreads();
        float entv = -accs[kp_ * 128 + 96 + b] * 0.12022458674074826f; // 1/log(4096+1e-6)
        float v = 0.f;
        if (t < 128) {
            const float* wr = sw1 + (size_t)t * 257;
            float acc = sb1[t];
#pragma unroll 8
            for (int i = 0; i < 256; ++i) acc += qs[i] * wr[i];
            acc += entv * wr[256];
            v = gelu_exact(acc) * sw2[t];
        }
#pragma unroll
        for (int off = 32; off > 0; off >>= 1) v += __shfl_down(v, off, 64);
        if (lane == 0) sred[wv] = v;
        __syncthreads();
        if (t == 0) {
            float sraw = sb2[0] + sred[0] + sred[1] + sred[2] + sred[3];
            out_stop[b * 6 + kp_] = 4.f * tanhf(sraw * 0.25f);
            out_cent[(b * 6 + kp_) * 2 + 0] = accs[kp_ * 128 + 32 + b];
            out_cent[(b * 6 + kp_) * 2 + 1] = accs[kp_ * 128 + 64 + b];
        }
        return;
    }
    // combine previous step's GRU gates -> h (state for this step)
    float h = 0.f;
    if (kstep > 0) {
        float sr = gacc[(b * 4 + 0) * 256 + t];
        float sz = gacc[(b * 4 + 1) * 256 + t];
        float gin = gacc[(b * 4 + 2) * 256 + t];
        float ghn = gacc[(b * 4 + 3) * 256 + t];
        float r = 1.f / (1.f + expf(-sr));
        float z = 1.f / (1.f + expf(-sz));
        float nv = tanhf(gin + r * ghn);
        h = (1.f - z) * nv + z * state_prev[b * 256 + t];
    }
    if (c == 0) state_cur[b * 256 + t] = h;
    // LN(clue + h)
    float x = clue[(b * 6 + kstep) * 256 + t] + h;
    float s = x, s2 = x * x;
#pragma unroll
    for (int off = 32; off > 0; off >>= 1) {
        s += __shfl_down(s, off, 64);
        s2 += __shfl_down(s2, off, 64);
    }
    if (lane == 0) { sred[wv] = s; sred[4 + wv] = s2; }
    __syncthreads();
    float muv = (sred[0] + sred[1] + sred[2] + sred[3]) * (1.f / 256.f);
    float var = (sred[4] + sred[5] + sred[6] + sred[7]) * (1.f / 256.f) - muv * muv;
    float rs = rsqrtf(var + 1e-5f);
    qs[t] = (x - muv) * rs * qn_g[t] + qn_b[t];
    __syncthreads();
    // q projection (each block computes the full q vector redundantly)
    const float4* wr = (const float4*)(q_w + (size_t)t * 256);
    const float4* xs4 = (const float4*)qs;
    float qv = q_b[t];
#pragma unroll 8
    for (int i = 0; i < 64; ++i) {
        float4 w = wr[i], xx = xs4[i];
        qv += w.x * xx.x + w.y * xx.y + w.z * xx.z + w.w * xx.w;
    }
    __syncthreads();
    qs[t] = qv;
    __syncthreads();
    // scores: 8 lanes per kp row (128B contiguous chunks), shfl_xor dot reduce
    int l = t & 7, rg = t >> 3;
    float dsum = 0.f;
#pragma unroll
    for (int pp = 0; pp < 8; ++pp) {
        int nl = pp * 32 + rg;
        int n = c * 256 + nl;
        const uint4* kr = reinterpret_cast<const uint4*>(kp + ((size_t)(b * 4096 + n)) * 256 + l * 8);
        float dot = 0.f;
#pragma unroll
        for (int j = 0; j < 4; ++j) {
            uint4 rv = kr[j * 8];                       // stride 64 elems = 128 B
            const float* qq = qs + j * 64 + l * 8;
            dot += bf2f(rv.x) * qq[0] + bf2f(rv.x >> 16) * qq[1]
                 + bf2f(rv.y) * qq[2] + bf2f(rv.y >> 16) * qq[3]
                 + bf2f(rv.z) * qq[4] + bf2f(rv.z >> 16) * qq[5]
                 + bf2f(rv.w) * qq[6] + bf2f(rv.w >> 16) * qq[7];
        }
        dot += __shfl_xor(dot, 1, 64);
        dot += __shfl_xor(dot, 2, 64);
        dot += __shfl_xor(dot, 4, 64);
        float sc = dot * 0.0625f + logf(mask[(size_t)b * 4096 + n]);
        sc = fminf(fmaxf(sc, -50.f), 50.f);
        float lg = fminf(fmaxf(sc * 2.f, -50.f), 50.f);   // /TEMP, TEMP=0.5
        float e = expf(lg);
        if (l == 0) {
            escore[(size_t)b * 4096 + n] = e;
            ash[nl] = e;
        }
        dsum += e;
    }
    dsum *= 0.125f;   // each e counted by 8 lanes
#pragma unroll
    for (int off = 32; off > 0; off >>= 1) dsum += __shfl_down(dsum, off, 64);
    if (lane == 0) sred[wv] = dsum;
    __syncthreads();
    if (t == 0) atomicAdd(&accs[kstep * 128 + b], sred[0] + sred[1] + sred[2] + sred[3]);
    // Σ e·v partials: thread owns 8 douts, sweeps 32 n rows (uint4 = 16B/lane)
    int dbase = (t & 31) * 8, noff = t >> 5;
    const unsigned short* vb = vp + ((size_t)(b * 4096 + c * 256 + noff * 32)) * 256 + dbase;
    float a0 = 0, a1 = 0, a2 = 0, a3 = 0, a4 = 0, a5 = 0, a6 = 0, a7 = 0;
#pragma unroll 4
    for (int j = 0; j < 32; ++j) {
        uint4 rv = *reinterpret_cast<const uint4*>(vb + (size_t)j * 256);
        float w = ash[noff * 32 + j];
        a0 += w * bf2f(rv.x); a1 += w * bf2f(rv.x >> 16);
        a2 += w * bf2f(rv.y); a3 += w * bf2f(rv.y >> 16);
        a4 += w * bf2f(rv.z); a5 += w * bf2f(rv.z >> 16);
        a6 += w * bf2f(rv.w); a7 += w * bf2f(rv.w >> 16);
    }
    *reinterpret_cast<float4*>(&part[noff][dbase])     = make_float4(a0, a1, a2, a3);
    *reinterpret_cast<float4*>(&part[noff][dbase + 4]) = make_float4(a4, a5, a6, a7);
    __syncthreads();
    float sum = part[0][t] + part[1][t] + part[2][t] + part[3][t]
              + part[4][t] + part[5][t] + part[6][t] + part[7][t];
    atomicAdd(&sumev[b * 256 + t], sum);
}

// ---------------- C: amap/centroid/entropy/mask (128 blk) + GRU gates (96 blk)
// + zero next sumev buffer (32 blk) ----------------
__global__ __launch_bounds__(256, 2) void k_attn2gate(
    const float* __restrict__ escore, float* __restrict__ mask,
    float* __restrict__ accs, float* __restrict__ out_amap,
    const float* __restrict__ sumev, float* __restrict__ sumev_zero,
    const float* __restrict__ state_cur,
    const float* __restrict__ wih, const float* __restrict__ bih,
    const float* __restrict__ whh, const float* __restrict__ bhh,
    float* __restrict__ gacc, int kstep) {
    int bb = blockIdx.x, t = threadIdx.x;
    int lane = t & 63, wv = t >> 6;
    __shared__ __align__(16) float att[256];
    __shared__ __align__(16) float st[256];
    __shared__ float sred[12];
    if (bb < 128) {
        int b = bb & 31, c = bb >> 5;
        int n4 = (c * 256 + t) * 4;
        float inv = 1.f / accs[kstep * 128 + b];
        float4 e4 = *reinterpret_cast<const float4*>(&escore[(size_t)b * 4096 + n4]);
        float4 m4 = *reinterpret_cast<const float4*>(&mask[(size_t)b * 4096 + n4]);
        float a[4] = {fmaxf(e4.x * inv, 1e-8f), fmaxf(e4.y * inv, 1e-8f),
                      fmaxf(e4.z * inv, 1e-8f), fmaxf(e4.w * inv, 1e-8f)};
        *reinterpret_cast<float4*>(&out_amap[((size_t)(b * 6 + kstep)) * 4096 + n4])
            = make_float4(a[0], a[1], a[2], a[3]);
        float mv[4] = {m4.x, m4.y, m4.z, m4.w};
        float s0 = 0.f, s1 = 0.f, s2 = 0.f;
#pragma unroll
        for (int j = 0; j < 4; ++j) {
            int n = n4 + j;
            s0 += a[j] * (float)(n >> 6);
            s1 += a[j] * (float)(n & 63);
            float ac = fmaxf(a[j], 1e-6f);
            s2 += ac * logf(ac);
            mv[j] = fmaxf(mv[j] * (1.f - 0.9f * a[j]), 1e-6f);
        }
        *reinterpret_cast<float4*>(&mask[(size_t)b * 4096 + n4])
            = make_float4(mv[0], mv[1], mv[2], mv[3]);
#pragma unroll
        for (int off = 32; off > 0; off >>= 1) {
            s0 += __shfl_down(s0, off, 64);
            s1 += __shfl_down(s1, off, 64);
            s2 += __shfl_down(s2, off, 64);
        }
        if (lane == 0) { sred[wv] = s0; sred[4 + wv] = s1; sred[8 + wv] = s2; }
        __syncthreads();
        if (t == 0) {
            atomicAdd(&accs[kstep * 128 + 32 + b], sred[0] + sred[1] + sred[2] + sred[3]);
            atomicAdd(&accs[kstep * 128 + 64 + b], sred[4] + sred[5] + sred[6] + sred[7]);
            atomicAdd(&accs[kstep * 128 + 96 + b], sred[8] + sred[9] + sred[10] + sred[11]);
        }
    } else if (bb < 224) {
        if (kstep == 5) return;   // gates feed h(k+1); unused after last step
        int b = (bb - 128) & 31, g = (bb - 128) >> 5;
        float inv = 1.f / accs[kstep * 128 + b];
        att[t] = sumev[b * 256 + t] * inv;
        st[t] = state_cur[b * 256 + t];
        __syncthreads();
        int row = g * 256 + t;
        const float4* wi = (const float4*)(wih + (size_t)row * 256);
        const float4* wh = (const float4*)(whh + (size_t)row * 256);
        const float4* av = (const float4*)att;
        const float4* sv = (const float4*)st;
        float ai = bih[row], ah = bhh[row];
#pragma unroll 4
        for (int i = 0; i < 64; ++i) {
            float4 w1 = wi[i], x1 = av[i];
            ai += w1.x * x1.x + w1.y * x1.y + w1.z * x1.z + w1.w * x1.w;
            float4 w2 = wh[i], x2 = sv[i];
            ah += w2.x * x2.x + w2.y * x2.y + w2.z * x2.z + w2.w * x2.w;
        }
        if (g == 2) {
            gacc[(b * 4 + 2) * 256 + t] = ai;
            gacc[(b * 4 + 3) * 256 + t] = ah;
        } else {
            gacc[(b * 4 + g) * 256 + t] = ai + ah;
        }
    } else {
        int b = bb - 224;
        sumev_zero[b * 256 + t] = 0.f;   // zero the buffer step k+1 accumulates into
    }
}

// ---------------- tail: stop head + centroid out for step 5 ----------------
__global__ void k_stop5(const float* __restrict__ sumev, const float* __restrict__ accs,
                        const float* __restrict__ sw1, const float* __restrict__ sb1,
                        const float* __restrict__ sw2, const float* __restrict__ sb2,
                        float* __restrict__ out_cent, float* __restrict__ out_stop) {
    int b = blockIdx.x, t = threadIdx.x;
    int lane = t & 63, wv = t >> 6;
    __shared__ __align__(16) float att[256];
    __shared__ float sred[4];
    float inv = 1.f / accs[5 * 128 + b];
    att[t] = sumev[b * 256 + t] * inv;
    __syncthreads();
    float entv = -accs[5 * 128 + 96 + b] * 0.12022458674074826f;
    float v = 0.f;
    if (t < 128) {
        const float* wr = sw1 + (size_t)t * 257;
        float acc = sb1[t];
#pragma unroll 8
        for (int i = 0; i < 256; ++i) acc += att[i] * wr[i];
        acc += entv * wr[256];
        v = gelu_exact(acc) * sw2[t];
    }
#pragma unroll
    for (int off = 32; off > 0; off >>= 1) v += __shfl_down(v, off, 64);
    if (lane == 0) sred[wv] = v;
    __syncthreads();
    if (t == 0) {
        float sraw = sb2[0] + sred[0] + sred[1] + sred[2] + sred[3];
        out_stop[b * 6 + 5] = 4.f * tanhf(sraw * 0.25f);
        out_cent[(b * 6 + 5) * 2 + 0] = accs[5 * 128 + 32 + b];
        out_cent[(b * 6 + 5) * 2 + 1] = accs[5 * 128 + 64 + b];
    }
}

extern "C" void kernel_launch(void* const* d_in, const int* in_sizes, int n_in,
                              void* d_out, int out_size, void* d_ws, size_t ws_size,
                              hipStream_t stream) {
    const float* features     = (const float*)d_in[0];
    const float* task_context = (const float*)d_in[1];
    const float* ctx_w1 = (const float*)d_in[2];
    const float* ctx_b1 = (const float*)d_in[3];
    const float* ctx_w2 = (const float*)d_in[4];
    const float* ctx_b2 = (const float*)d_in[5];
    const float* q_w = (const float*)d_in[6];
    const float* q_b = (const float*)d_in[7];
    const float* k_w = (const float*)d_in[8];
    const float* k_b = (const float*)d_in[9];
    const float* v_w = (const float*)d_in[10];
    const float* v_b = (const float*)d_in[11];
    const float* qn_g = (const float*)d_in[12];
    const float* qn_b = (const float*)d_in[13];
    const float* fn_g = (const float*)d_in[14];
    const float* fn_b = (const float*)d_in[15];
    const float* stop_w1 = (const float*)d_in[16];
    const float* stop_b1 = (const float*)d_in[17];
    const float* stop_w2 = (const float*)d_in[18];
    const float* stop_b2 = (const float*)d_in[19];
    const float* gru_wih = (const float*)d_in[20];
    const float* gru_bih = (const float*)d_in[21];
    const float* gru_whh = (const float*)d_in[22];
    const float* gru_bhh = (const float*)d_in[23];

    // workspace layout (~136 MB)
    unsigned short* kwb = (unsigned short*)d_ws;
    unsigned short* vwb = kwb + 65536;
    unsigned short* kp  = vwb + 65536;
    unsigned short* vp  = kp + (size_t)NB * NN_ * ND;
    float* clue     = (float*)(vp + (size_t)NB * NN_ * ND);
    float* state0   = clue + NB * NK * ND;
    float* state1   = state0 + NB * ND;
    float* sumev0   = state1 + NB * ND;
    float* sumev1   = sumev0 + NB * ND;
    float* mask     = sumev1 + NB * ND;
    float* escore   = mask + NB * NN_;
    float* accs     = escore + NB * NN_;      // [6][4][32]: denom,rowc,colc,ent
    float* gacc     = accs + NK * 4 * NB;     // [32][4][256]

    float* out_cent = (float*)d_out;          // (B,K,2)
    float* out_amap = out_cent + NB * NK * 2; // (B,K,H,W)
    float* out_stop = out_amap + (size_t)NB * NK * NN_; // (B,K)

    float* stbuf[2] = {state0, state1};
    float* evbuf[2] = {sumev0, sumev1};

    k_setup<<<1091, 256, 0, stream>>>(k_w, v_w, kwb, vwb, mask, accs, sumev0,
                                      task_context, ctx_w1, ctx_b1, ctx_w2, ctx_b2, clue);
    k_kv<<<dim3(32, 32), 256, 0, stream>>>(features, fn_g, fn_b, kwb, vwb, k_b, v_b, kp, vp);
    for (int k = 0; k < NK; ++k) {
        float* scur = stbuf[k & 1];
        float* sprev = stbuf[1 - (k & 1)];
        float* ev = evbuf[k & 1];
        float* evo = evbuf[1 - (k & 1)];
        k_qscore<<<dim3(17, 32), 256, 0, stream>>>(clue, gacc, sprev, scur, qn_g, qn_b,
                                                   q_w, q_b, kp, vp, mask, escore, accs,
                                                   ev, evo, stop_w1, stop_b1, stop_w2, stop_b2,
                                                   out_cent, out_stop, k);
        k_attn2gate<<<256, 256, 0, stream>>>(escore, mask, accs, out_amap, ev, evo, scur,
                                             gru_wih, gru_bih, gru_whh, gru_bhh, gacc, k);
    }
    k_stop5<<<32, 256, 0, stream>>>(evbuf[1], accs, stop_w1, stop_b1, stop_w2, stop_b2,
                                    out_cent, out_stop);
}